// Round 1
// baseline (511.231 us; speedup 1.0000x reference)
//
#include <hip/hip_runtime.h>
#include <hip/hip_bf16.h>

#define P_TOTAL 160000
#define NPB     40000      // points per batch (B=4)
#define NCLS    13
#define TP      64         // points per block

typedef __attribute__((ext_vector_type(8))) short bf16x8;   // 8 bf16 in 4 VGPRs
typedef __attribute__((ext_vector_type(4))) float f32x4;

__device__ __forceinline__ ushort f2bf(float f) {
  union { float f; unsigned u; } v; v.f = f;
  unsigned r = v.u + 0x7fff + ((v.u >> 16) & 1);   // RNE
  return (ushort)(r >> 16);
}

// ---------------- weight prep: fp32 [k][n] -> bf16 transposed [n][k] ----------------
// WT1: [256][32] (k<7 real, rest 0)   WT2: [512][256]   WT3: [256][512]   WT4: [128][256]
__global__ void prep_kernel(const float* __restrict__ We1, const float* __restrict__ We2,
                            const float* __restrict__ W1,  const float* __restrict__ W2,
                            ushort* __restrict__ WT1, ushort* __restrict__ WT2,
                            ushort* __restrict__ WT3, ushort* __restrict__ WT4,
                            int* __restrict__ counts, float* __restrict__ gsums) {
  int tid = threadIdx.x;
  if (blockIdx.x == 0) {           // zero the atomics region (ws is poisoned 0xAA)
    if (tid < 16) counts[tid] = 0;
    for (int i = tid; i < NCLS * 128; i += 256) gsums[i] = 0.f;
  }
  const int T1 = 8192, T2 = T1 + 131072, T3 = T2 + 131072, T4 = T3 + 32768;
  for (int i = blockIdx.x * 256 + tid; i < T4; i += gridDim.x * 256) {
    if (i < T1) {
      int n = i >> 5, k = i & 31;
      WT1[i] = (k < 7) ? f2bf(We1[k * 256 + n]) : (ushort)0;
    } else if (i < T2) {
      int j = i - T1; int n = j >> 8, k = j & 255;
      WT2[j] = f2bf(We2[k * 512 + n]);
    } else if (i < T3) {
      int j = i - T2; int n = j >> 9, k = j & 511;
      WT3[j] = f2bf(W1[k * 256 + n]);
    } else {
      int j = i - T3; int n = j >> 8, k = j & 255;
      WT4[j] = f2bf(W2[k * 128 + n]);
    }
  }
}

// ---------------- label histogram ----------------
__global__ void counts_kernel(const int* __restrict__ y, int* __restrict__ counts) {
  __shared__ int h[NCLS];
  int tid = threadIdx.x;
  if (tid < NCLS) h[tid] = 0;
  __syncthreads();
  for (int i = blockIdx.x * 256 + tid; i < P_TOTAL; i += gridDim.x * 256)
    atomicAdd(&h[y[i]], 1);
  __syncthreads();
  if (tid < NCLS) atomicAdd(&counts[tid], h[tid]);
}

// ---------------- one MFMA layer: [TP x KIN] @ WT[KOUT][KIN]^T -> [TP x KOUT] ----------------
// A-frag: A[m=lane&15][k=quad*8+j] ; B-frag from WT rows (contiguous k) ; C/D: col=lane&15,row=quad*4+r
template<int KIN, int IN_STRIDE, int KOUT, int OUT_STRIDE, int NTILES, bool OUT_F32>
__device__ __forceinline__ void gemm_layer(const ushort* __restrict__ in,
                                           ushort* __restrict__ outb, float* __restrict__ outf,
                                           const ushort* __restrict__ W,
                                           const float* __restrict__ bias,
                                           int wave, int lane) {
  constexpr int CPW = KOUT / 4;          // columns per wave
  constexpr int CHUNK = NTILES * 16;
  const int n0w  = wave * CPW;
  const int mrow = lane & 15;
  const int quad = lane >> 4;
  for (int nc = 0; nc < CPW; nc += CHUNK) {
    f32x4 acc[4][NTILES];
    const f32x4 zero = {0.f, 0.f, 0.f, 0.f};
    #pragma unroll
    for (int mt = 0; mt < 4; mt++)
      #pragma unroll
      for (int nt = 0; nt < NTILES; nt++) acc[mt][nt] = zero;

    for (int k = 0; k < KIN; k += 32) {
      int kl = k + (quad << 3);
      bf16x8 af[4], bfr[NTILES];
      #pragma unroll
      for (int mt = 0; mt < 4; mt++)
        af[mt] = *(const bf16x8*)(in + (mt * 16 + mrow) * IN_STRIDE + kl);
      #pragma unroll
      for (int nt = 0; nt < NTILES; nt++)
        bfr[nt] = *(const bf16x8*)(W + (n0w + nc + nt * 16 + mrow) * KIN + kl);
      #pragma unroll
      for (int nt = 0; nt < NTILES; nt++)
        #pragma unroll
        for (int mt = 0; mt < 4; mt++)
          acc[mt][nt] = __builtin_amdgcn_mfma_f32_16x16x32_bf16(af[mt], bfr[nt], acc[mt][nt], 0, 0, 0);
    }

    #pragma unroll
    for (int nt = 0; nt < NTILES; nt++) {
      int n = n0w + nc + nt * 16 + mrow;
      float bv = bias[n];
      #pragma unroll
      for (int mt = 0; mt < 4; mt++) {
        #pragma unroll
        for (int r = 0; r < 4; r++) {
          float v = fmaxf(acc[mt][nt][r] + bv, 0.f);
          int m = mt * 16 + quad * 4 + r;
          if (OUT_F32) outf[m * OUT_STRIDE + n] = v;
          else         outb[m * OUT_STRIDE + n] = f2bf(v);
        }
      }
    }
  }
}

// ---------------- fused MLP + norm + output + class sums ----------------
__global__ __launch_bounds__(256) void main_kernel(
    const float* __restrict__ pos, const float* __restrict__ x, const int* __restrict__ y,
    const float* __restrict__ be1, const float* __restrict__ be2,
    const float* __restrict__ b1,  const float* __restrict__ b2,
    const ushort* __restrict__ WT1, const ushort* __restrict__ WT2,
    const ushort* __restrict__ WT3, const ushort* __restrict__ WT4,
    const int* __restrict__ counts, float* __restrict__ gsums,
    float* __restrict__ out) {
  __shared__ ushort bufA[TP * 520];      // 66560 B: A0[64][40] -> L2 out [64][512+8] -> feat fp32 [64][132]
  __shared__ ushort bufB[TP * 264];      // 33792 B: 256-wide activations (+8 pad)
  __shared__ float  part[TP * 4];
  __shared__ float  inv_norm[TP];
  __shared__ int    lbl[TP];
  __shared__ float  lbl_eff[TP];

  int tid  = threadIdx.x;
  int wave = tid >> 6, lane = tid & 63;
  long p0 = (long)blockIdx.x * TP;       // 40000 % 64 == 0 -> block never spans batches
  int b  = (int)(p0 / NPB);
  int n0 = (int)(p0 % NPB);

  // stage A0 = [x(4) | pos(3) | 0...] as bf16, stride 40 (16B-aligned rows)
  for (int i = tid; i < TP * 40; i += 256) {
    int r = i / 40, k = i - r * 40;
    float v = 0.f;
    if (k < 4)      v = x[(b * 4 + k) * NPB + n0 + r];
    else if (k < 7) v = pos[(p0 + r) * 3 + (k - 4)];
    bufA[r * 40 + k] = f2bf(v);
  }
  if (tid < TP) lbl[tid] = y[p0 + tid];
  __syncthreads();

  gemm_layer< 32,  40, 256, 264, 4, false>(bufA, bufB, nullptr, WT1, be1, wave, lane);
  __syncthreads();
  gemm_layer<256, 264, 512, 520, 4, false>(bufB, bufA, nullptr, WT2, be2, wave, lane);
  __syncthreads();
  gemm_layer<512, 520, 256, 264, 4, false>(bufA, bufB, nullptr, WT3, b1, wave, lane);
  __syncthreads();
  float* feat = (float*)bufA;            // [TP][132] fp32, overlays bufA (dead)
  gemm_layer<256, 264, 128, 132, 2, true >(bufB, nullptr, feat, WT4, b2, wave, lane);
  __syncthreads();

  // row L2 norms (4 threads per row)
  {
    int r = tid & 63, q = tid >> 6;
    float s = 0.f;
    #pragma unroll
    for (int c = 0; c < 32; c++) { float v = feat[r * 132 + q * 32 + c]; s += v * v; }
    part[r * 4 + q] = s;
  }
  __syncthreads();
  if (tid < TP) {
    float ss = part[tid * 4] + part[tid * 4 + 1] + part[tid * 4 + 2] + part[tid * 4 + 3];
    inv_norm[tid] = 1.f / fmaxf(sqrtf(ss), 1e-12f);
    int l = lbl[tid];
    lbl_eff[tid] = (counts[l] >= 256) ? (float)l : -1.f;   // MIN_PTS gate
  }
  __syncthreads();

  // current_prior rows [p0, p0+TP): 128 normalized feats + label column (fully contiguous store)
  for (int i = tid; i < TP * 129; i += 256) {
    int r = i / 129, k = i - r * 129;
    float v = (k < 128) ? feat[r * 132 + k] * inv_norm[r] : lbl_eff[r];
    out[p0 * 129 + i] = v;
  }

  // per-class partial sums of normalized feat; register accumulators (no dynamic indexing)
  if (tid < 128) {
    float a[NCLS];
    #pragma unroll
    for (int c = 0; c < NCLS; c++) a[c] = 0.f;
    for (int r = 0; r < TP; r++) {
      float v = feat[r * 132 + tid] * inv_norm[r];
      int cls = lbl[r];
      #pragma unroll
      for (int c = 0; c < NCLS; c++) a[c] += (cls == c) ? v : 0.f;
    }
    #pragma unroll
    for (int c = 0; c < NCLS; c++) atomicAdd(&gsums[c * 128 + tid], a[c]);
  }
}

// ---------------- EMA + renorm of prior ----------------
__global__ void finalize_kernel(const float* __restrict__ prior, const int* __restrict__ counts,
                                const float* __restrict__ gsums, float* __restrict__ out) {
  __shared__ float v[NCLS * 128];
  __shared__ float invn[NCLS];
  int tid = threadIdx.x;
  for (int i = tid; i < NCLS * 128; i += 256) {
    int cls = i >> 7;
    int cnt = counts[cls];
    float mean = gsums[i] / fmaxf((float)cnt, 1.f);
    float cur  = (cnt >= 256) ? mean : prior[i];
    v[i] = 0.999f * prior[i] + 0.001f * cur;
  }
  __syncthreads();
  if (tid < NCLS) {
    float s = 0.f;
    for (int c = 0; c < 128; c++) { float t = v[tid * 128 + c]; s += t * t; }
    invn[tid] = 1.f / fmaxf(sqrtf(s), 1e-12f);
  }
  __syncthreads();
  for (int i = tid; i < NCLS * 128; i += 256)
    out[(long)P_TOTAL * 129 + i] = v[i] * invn[i >> 7];
}

extern "C" void kernel_launch(void* const* d_in, const int* in_sizes, int n_in,
                              void* d_out, int out_size, void* d_ws, size_t ws_size,
                              hipStream_t stream) {
  const float* pos   = (const float*)d_in[0];
  const float* x     = (const float*)d_in[1];
  const int*   y     = (const int*)  d_in[2];
  const float* We1   = (const float*)d_in[3];
  const float* be1   = (const float*)d_in[4];
  const float* We2   = (const float*)d_in[5];
  const float* be2   = (const float*)d_in[6];
  const float* W1    = (const float*)d_in[7];
  const float* b1    = (const float*)d_in[8];
  const float* W2    = (const float*)d_in[9];
  const float* b2    = (const float*)d_in[10];
  const float* prior = (const float*)d_in[11];
  float* out = (float*)d_out;

  char* ws = (char*)d_ws;
  int*    counts = (int*)   (ws + 0);        //    64 B
  float*  gsums  = (float*) (ws + 256);      //  6656 B
  ushort* WT1    = (ushort*)(ws + 8192);     // 16384 B
  ushort* WT2    = (ushort*)(ws + 24576);    // 262144 B
  ushort* WT3    = (ushort*)(ws + 286720);   // 262144 B
  ushort* WT4    = (ushort*)(ws + 548864);   // 65536 B   (total 614400 B of ws)

  prep_kernel    <<<512, 256, 0, stream>>>(We1, We2, W1, W2, WT1, WT2, WT3, WT4, counts, gsums);
  counts_kernel  <<<400, 256, 0, stream>>>(y, counts);
  main_kernel    <<<P_TOTAL / TP, 256, 0, stream>>>(pos, x, y, be1, be2, b1, b2,
                                                    WT1, WT2, WT3, WT4, counts, gsums, out);
  finalize_kernel<<<1, 256, 0, stream>>>(prior, counts, gsums, out);
}

// Round 2
// 426.163 us; speedup vs baseline: 1.1996x; 1.1996x over previous
//
#include <hip/hip_runtime.h>
#include <hip/hip_bf16.h>

#define P_TOTAL 160000
#define NPB     40000      // points per batch (B=4)
#define NCLS    13
#define TP      64         // points per block

typedef __attribute__((ext_vector_type(8))) short bf16x8;   // 8 bf16 in 4 VGPRs
typedef __attribute__((ext_vector_type(4))) float f32x4;

__device__ __forceinline__ ushort f2bf(float f) {
  union { float f; unsigned u; } v; v.f = f;
  unsigned r = v.u + 0x7fff + ((v.u >> 16) & 1);   // RNE
  return (ushort)(r >> 16);
}
__device__ __forceinline__ float bf2f(ushort u) {
  union { unsigned u; float f; } v; v.u = ((unsigned)u) << 16;
  return v.f;
}

// ---------------- small prep: W1 transpose + zero atomics region ----------------
__global__ void small_prep_kernel(const float* __restrict__ We1, ushort* __restrict__ WT1,
                                  int* __restrict__ counts, float* __restrict__ gsums) {
  int tid = threadIdx.x;
  if (tid < 16) counts[tid] = 0;
  for (int i = tid; i < NCLS * 128; i += 256) gsums[i] = 0.f;
  for (int i = tid; i < 8192; i += 256) {       // WT1: [256][32], k<7 real
    int n = i >> 5, k = i & 31;
    WT1[i] = (k < 7) ? f2bf(We1[k * 256 + n]) : (ushort)0;
  }
}

// ---------------- tiled transpose: src fp32 [K][N] -> dst bf16 [N][K] ----------------
__global__ void transpose_kernel(const float* __restrict__ src, ushort* __restrict__ dst,
                                 int K, int N) {
  __shared__ ushort t[32][33];
  int ntx = N >> 5;
  int n0 = (blockIdx.x % ntx) << 5;
  int k0 = (blockIdx.x / ntx) << 5;
  int c = threadIdx.x & 31, r = threadIdx.x >> 5;   // 8 rows of 32
  #pragma unroll
  for (int rr = 0; rr < 32; rr += 8)
    t[r + rr][c] = f2bf(src[(k0 + r + rr) * N + n0 + c]);
  __syncthreads();
  #pragma unroll
  for (int rr = 0; rr < 32; rr += 8)
    dst[(long)(n0 + r + rr) * K + k0 + c] = t[c][r + rr];
}

// ---------------- label histogram ----------------
__global__ void counts_kernel(const int* __restrict__ y, int* __restrict__ counts) {
  __shared__ int h[NCLS];
  int tid = threadIdx.x;
  if (tid < NCLS) h[tid] = 0;
  __syncthreads();
  for (int i = blockIdx.x * 256 + tid; i < P_TOTAL; i += gridDim.x * 256)
    atomicAdd(&h[y[i]], 1);
  __syncthreads();
  if (tid < NCLS) atomicAdd(&counts[tid], h[tid]);
}

// ---------------- fused MLP (L2/L3 k-chunked) + norm + output + class sums ----------------
// Layouts (measured, learn_hip m89/m91): A[m=lane&15][k=quad*8+j]; B[n=lane&15][k=quad*8+j];
// C/D: col=lane&15, row=quad*4+reg.
__global__ __launch_bounds__(256, 2) void main_kernel(
    const float* __restrict__ pos, const float* __restrict__ x, const int* __restrict__ y,
    const float* __restrict__ be1, const float* __restrict__ be2,
    const float* __restrict__ b1,  const float* __restrict__ b2,
    const ushort* __restrict__ WT1, const ushort* __restrict__ WT2,
    const ushort* __restrict__ WT3, const ushort* __restrict__ WT4,
    const int* __restrict__ counts, float* __restrict__ gsums,
    float* __restrict__ out) {
  __shared__ ushort actbuf[TP * 264];     // 33792 B: act1 [64][256+8], later act3
  __shared__ ushort chunkbuf[TP * 136];   // 17408 B: A0 [64][40] -> act2 chunks [64][128+8] -> feat bf16
  __shared__ float  part[TP * 4];
  __shared__ float  inv_norm[TP];
  __shared__ int    lbl[TP];
  __shared__ float  lbl_eff[TP];

  const int tid  = threadIdx.x;
  const int wave = tid >> 6, lane = tid & 63;
  const int quad = lane >> 4, mrow = lane & 15;
  const long p0 = (long)blockIdx.x * TP;   // 40000 % 64 == 0: block never spans batches
  const int b  = (int)(p0 / NPB);
  const int n0 = (int)(p0 % NPB);
  const f32x4 zero = {0.f, 0.f, 0.f, 0.f};

  // ---- stage A0 = [x(4) | pos(3) | 0...] bf16, stride 40 ----
  for (int i = tid; i < TP * 40; i += 256) {
    int r = i / 40, k = i - r * 40;
    float v = 0.f;
    if (k < 4)      v = x[(b * 4 + k) * NPB + n0 + r];
    else if (k < 7) v = pos[(p0 + r) * 3 + (k - 4)];
    chunkbuf[r * 40 + k] = f2bf(v);
  }
  if (tid < TP) lbl[tid] = y[p0 + tid];
  __syncthreads();

  // ---- L1: [64x32] @ WT1[256][32]^T -> act1 [64][256]; wave cols n0w1 = wave*64 ----
  {
    const int n0w = wave * 64;
    f32x4 acc[4][4];
    #pragma unroll
    for (int mt = 0; mt < 4; mt++)
      #pragma unroll
      for (int nt = 0; nt < 4; nt++) acc[mt][nt] = zero;
    const int kl = quad << 3;
    bf16x8 af[4], bf[4];
    #pragma unroll
    for (int mt = 0; mt < 4; mt++)
      af[mt] = *(const bf16x8*)(chunkbuf + (mt * 16 + mrow) * 40 + kl);
    #pragma unroll
    for (int nt = 0; nt < 4; nt++)
      bf[nt] = *(const bf16x8*)(WT1 + (n0w + nt * 16 + mrow) * 32 + kl);
    #pragma unroll
    for (int nt = 0; nt < 4; nt++)
      #pragma unroll
      for (int mt = 0; mt < 4; mt++)
        acc[mt][nt] = __builtin_amdgcn_mfma_f32_16x16x32_bf16(af[mt], bf[nt], acc[mt][nt], 0, 0, 0);
    #pragma unroll
    for (int nt = 0; nt < 4; nt++) {
      int n = n0w + nt * 16 + mrow;
      float bv = be1[n];
      #pragma unroll
      for (int mt = 0; mt < 4; mt++)
        #pragma unroll
        for (int r = 0; r < 4; r++)
          actbuf[(mt * 16 + quad * 4 + r) * 264 + n] = f2bf(fmaxf(acc[mt][nt][r] + bv, 0.f));
    }
  }
  __syncthreads();

  // ---- fused L2+L3: act2 in 4 chunks of 128 cols; acc3 held in regs ----
  f32x4 acc3[4][4];                       // L3 cols n0w3 = wave*64
  #pragma unroll
  for (int mt = 0; mt < 4; mt++)
    #pragma unroll
    for (int nt = 0; nt < 4; nt++) acc3[mt][nt] = zero;
  const int n0w3 = wave * 64;

  for (int c = 0; c < 4; c++) {
    // L2 chunk: wave computes act2 cols [c*128 + wave*32, +32)
    f32x4 acc2[4][2];
    #pragma unroll
    for (int mt = 0; mt < 4; mt++) { acc2[mt][0] = zero; acc2[mt][1] = zero; }
    for (int ks = 0; ks < 8; ks++) {
      const int kl = ks * 32 + (quad << 3);
      bf16x8 af[4], bf2[2];
      #pragma unroll
      for (int mt = 0; mt < 4; mt++)
        af[mt] = *(const bf16x8*)(actbuf + (mt * 16 + mrow) * 264 + kl);
      #pragma unroll
      for (int nt = 0; nt < 2; nt++)
        bf2[nt] = *(const bf16x8*)(WT2 + (long)(c * 128 + wave * 32 + nt * 16 + mrow) * 256 + kl);
      #pragma unroll
      for (int nt = 0; nt < 2; nt++)
        #pragma unroll
        for (int mt = 0; mt < 4; mt++)
          acc2[mt][nt] = __builtin_amdgcn_mfma_f32_16x16x32_bf16(af[mt], bf2[nt], acc2[mt][nt], 0, 0, 0);
    }
    __syncthreads();   // prev chunk's (or A0's) chunkbuf readers done
    #pragma unroll
    for (int nt = 0; nt < 2; nt++) {
      int lc = wave * 32 + nt * 16 + mrow;            // chunk-local col
      float bv = be2[c * 128 + lc];
      #pragma unroll
      for (int mt = 0; mt < 4; mt++)
        #pragma unroll
        for (int r = 0; r < 4; r++)
          chunkbuf[(mt * 16 + quad * 4 + r) * 136 + lc] = f2bf(fmaxf(acc2[mt][nt][r] + bv, 0.f));
    }
    __syncthreads();
    // L3 accumulate over this chunk's 128 k values
    for (int ks = 0; ks < 4; ks++) {
      const int kl = ks * 32 + (quad << 3);
      bf16x8 af[4], bf[4];
      #pragma unroll
      for (int mt = 0; mt < 4; mt++)
        af[mt] = *(const bf16x8*)(chunkbuf + (mt * 16 + mrow) * 136 + kl);
      #pragma unroll
      for (int nt = 0; nt < 4; nt++)
        bf[nt] = *(const bf16x8*)(WT3 + (long)(n0w3 + nt * 16 + mrow) * 512 + c * 128 + kl);
      #pragma unroll
      for (int nt = 0; nt < 4; nt++)
        #pragma unroll
        for (int mt = 0; mt < 4; mt++)
          acc3[mt][nt] = __builtin_amdgcn_mfma_f32_16x16x32_bf16(af[mt], bf[nt], acc3[mt][nt], 0, 0, 0);
    }
  }

  // ---- L3 epilogue -> act3 into actbuf (act1 dead; all act1 reads pre-date last barrier) ----
  #pragma unroll
  for (int nt = 0; nt < 4; nt++) {
    int n = n0w3 + nt * 16 + mrow;
    float bv = b1[n];
    #pragma unroll
    for (int mt = 0; mt < 4; mt++)
      #pragma unroll
      for (int r = 0; r < 4; r++)
        actbuf[(mt * 16 + quad * 4 + r) * 264 + n] = f2bf(fmaxf(acc3[mt][nt][r] + bv, 0.f));
  }
  __syncthreads();

  // ---- L4: [64x256] @ WT4[128][256]^T -> feat bf16 into chunkbuf; wave cols n0w4 = wave*32 ----
  {
    const int n0w4 = wave * 32;
    f32x4 acc4[4][2];
    #pragma unroll
    for (int mt = 0; mt < 4; mt++) { acc4[mt][0] = zero; acc4[mt][1] = zero; }
    for (int ks = 0; ks < 8; ks++) {
      const int kl = ks * 32 + (quad << 3);
      bf16x8 af[4], bf2[2];
      #pragma unroll
      for (int mt = 0; mt < 4; mt++)
        af[mt] = *(const bf16x8*)(actbuf + (mt * 16 + mrow) * 264 + kl);
      #pragma unroll
      for (int nt = 0; nt < 2; nt++)
        bf2[nt] = *(const bf16x8*)(WT4 + (long)(n0w4 + nt * 16 + mrow) * 256 + kl);
      #pragma unroll
      for (int nt = 0; nt < 2; nt++)
        #pragma unroll
        for (int mt = 0; mt < 4; mt++)
          acc4[mt][nt] = __builtin_amdgcn_mfma_f32_16x16x32_bf16(af[mt], bf2[nt], acc4[mt][nt], 0, 0, 0);
    }
    #pragma unroll
    for (int nt = 0; nt < 2; nt++) {
      int n = n0w4 + nt * 16 + mrow;
      float bv = b2[n];
      #pragma unroll
      for (int mt = 0; mt < 4; mt++)
        #pragma unroll
        for (int r = 0; r < 4; r++)
          chunkbuf[(mt * 16 + quad * 4 + r) * 136 + n] = f2bf(fmaxf(acc4[mt][nt][r] + bv, 0.f));
    }
  }
  __syncthreads();

  // ---- row L2 norms (4 threads per row, bf16 feat at stride 136) ----
  {
    int r = tid & 63, q = tid >> 6;
    float s = 0.f;
    #pragma unroll
    for (int cc = 0; cc < 32; cc++) {
      float v = bf2f(chunkbuf[r * 136 + q * 32 + cc]);
      s += v * v;
    }
    part[r * 4 + q] = s;
  }
  __syncthreads();
  if (tid < TP) {
    float ss = part[tid * 4] + part[tid * 4 + 1] + part[tid * 4 + 2] + part[tid * 4 + 3];
    inv_norm[tid] = 1.f / fmaxf(sqrtf(ss), 1e-12f);
    int l = lbl[tid];
    lbl_eff[tid] = (counts[l] >= 256) ? (float)l : -1.f;   // MIN_PTS gate
  }
  __syncthreads();

  // ---- current_prior rows: 128 normalized feats + label column ----
  for (int i = tid; i < TP * 129; i += 256) {
    int r = i / 129, k = i - r * 129;
    float v = (k < 128) ? bf2f(chunkbuf[r * 136 + k]) * inv_norm[r] : lbl_eff[r];
    out[p0 * 129 + i] = v;
  }

  // ---- per-class partial sums of normalized feat ----
  if (tid < 128) {
    float a[NCLS];
    #pragma unroll
    for (int cc = 0; cc < NCLS; cc++) a[cc] = 0.f;
    for (int r = 0; r < TP; r++) {
      float v = bf2f(chunkbuf[r * 136 + tid]) * inv_norm[r];
      int cls = lbl[r];
      #pragma unroll
      for (int cc = 0; cc < NCLS; cc++) a[cc] += (cls == cc) ? v : 0.f;
    }
    #pragma unroll
    for (int cc = 0; cc < NCLS; cc++) atomicAdd(&gsums[cc * 128 + tid], a[cc]);
  }
}

// ---------------- EMA + renorm of prior ----------------
__global__ void finalize_kernel(const float* __restrict__ prior, const int* __restrict__ counts,
                                const float* __restrict__ gsums, float* __restrict__ out) {
  __shared__ float v[NCLS * 128];
  __shared__ float invn[NCLS];
  int tid = threadIdx.x;
  for (int i = tid; i < NCLS * 128; i += 256) {
    int cls = i >> 7;
    int cnt = counts[cls];
    float mean = gsums[i] / fmaxf((float)cnt, 1.f);
    float cur  = (cnt >= 256) ? mean : prior[i];
    v[i] = 0.999f * prior[i] + 0.001f * cur;
  }
  __syncthreads();
  if (tid < NCLS) {
    float s = 0.f;
    for (int c = 0; c < 128; c++) { float t = v[tid * 128 + c]; s += t * t; }
    invn[tid] = 1.f / fmaxf(sqrtf(s), 1e-12f);
  }
  __syncthreads();
  for (int i = tid; i < NCLS * 128; i += 256)
    out[(long)P_TOTAL * 129 + i] = v[i] * invn[i >> 7];
}

extern "C" void kernel_launch(void* const* d_in, const int* in_sizes, int n_in,
                              void* d_out, int out_size, void* d_ws, size_t ws_size,
                              hipStream_t stream) {
  const float* pos   = (const float*)d_in[0];
  const float* x     = (const float*)d_in[1];
  const int*   y     = (const int*)  d_in[2];
  const float* We1   = (const float*)d_in[3];
  const float* be1   = (const float*)d_in[4];
  const float* We2   = (const float*)d_in[5];
  const float* be2   = (const float*)d_in[6];
  const float* W1    = (const float*)d_in[7];
  const float* b1    = (const float*)d_in[8];
  const float* W2    = (const float*)d_in[9];
  const float* b2    = (const float*)d_in[10];
  const float* prior = (const float*)d_in[11];
  float* out = (float*)d_out;

  char* ws = (char*)d_ws;
  int*    counts = (int*)   (ws + 0);        //    64 B
  float*  gsums  = (float*) (ws + 256);      //  6656 B
  ushort* WT1    = (ushort*)(ws + 8192);     // 16384 B  [256][32]
  ushort* WT2    = (ushort*)(ws + 24576);    // 262144 B [512][256]
  ushort* WT3    = (ushort*)(ws + 286720);   // 262144 B [256][512]
  ushort* WT4    = (ushort*)(ws + 548864);   // 65536 B  [128][256]

  small_prep_kernel<<<1, 256, 0, stream>>>(We1, WT1, counts, gsums);
  transpose_kernel <<<(512/32)*(256/32), 256, 0, stream>>>(We2, WT2, 256, 512);  // -> [512][256]
  transpose_kernel <<<(256/32)*(512/32), 256, 0, stream>>>(W1,  WT3, 512, 256);  // -> [256][512]
  transpose_kernel <<<(128/32)*(256/32), 256, 0, stream>>>(W2,  WT4, 256, 128);  // -> [128][256]
  counts_kernel    <<<400, 256, 0, stream>>>(y, counts);
  main_kernel      <<<P_TOTAL / TP, 256, 0, stream>>>(pos, x, y, be1, be2, b1, b2,
                                                      WT1, WT2, WT3, WT4, counts, gsums, out);
  finalize_kernel  <<<1, 256, 0, stream>>>(prior, counts, gsums, out);
}

// Round 3
// 354.277 us; speedup vs baseline: 1.4430x; 1.2029x over previous
//
#include <hip/hip_runtime.h>
#include <hip/hip_bf16.h>

#define P_TOTAL 160000
#define NPB     40000      // points per batch (B=4)
#define NCLS    13
#define TP      64         // points per block

typedef __attribute__((ext_vector_type(8))) short bf16x8;   // 8 bf16 in 4 VGPRs
typedef __attribute__((ext_vector_type(4))) float f32x4;

__device__ __forceinline__ ushort f2bf(float f) {
  union { float f; unsigned u; } v; v.f = f;
  unsigned r = v.u + 0x7fff + ((v.u >> 16) & 1);   // RNE
  return (ushort)(r >> 16);
}

// ---------------- fused prep: transposes + WT1 + histogram ----------------
// blocks 0..127: WT2 (We2 [256][512] -> [512][256]); 128..255: WT3 (W1 [512][256] -> [256][512]);
// 256..287: WT4 (W2 [256][128] -> [128][256]); 288: WT1; 289..415: label histogram.
__device__ __forceinline__ void transpose_tile(const float* __restrict__ src,
                                               ushort* __restrict__ dst,
                                               int K, int N, int tile, ushort (*t)[33]) {
  int ntx = N >> 5;
  int n0 = (tile % ntx) << 5, k0 = (tile / ntx) << 5;
  int c = threadIdx.x & 31, r = threadIdx.x >> 5;   // 8 rows of 32
  #pragma unroll
  for (int rr = 0; rr < 32; rr += 8)
    t[r + rr][c] = f2bf(src[(k0 + r + rr) * N + n0 + c]);
  __syncthreads();
  #pragma unroll
  for (int rr = 0; rr < 32; rr += 8)
    dst[(n0 + r + rr) * K + k0 + c] = t[c][r + rr];
}

__global__ void prep_all_kernel(const float* __restrict__ We1, const float* __restrict__ We2,
                                const float* __restrict__ W1,  const float* __restrict__ W2,
                                const int* __restrict__ y,
                                ushort* __restrict__ WT1, ushort* __restrict__ WT2,
                                ushort* __restrict__ WT3, ushort* __restrict__ WT4,
                                int* __restrict__ counts) {
  __shared__ ushort t[32][33];
  __shared__ int h[NCLS];
  int b = blockIdx.x, tid = threadIdx.x;
  if (b < 128)       transpose_tile(We2, WT2, 256, 512, b, t);
  else if (b < 256)  transpose_tile(W1,  WT3, 512, 256, b - 128, t);
  else if (b < 288)  transpose_tile(W2,  WT4, 256, 128, b - 256, t);
  else if (b == 288) {
    for (int i = tid; i < 8192; i += 256) {        // WT1: [256][32], k<7 real
      int n = i >> 5, k = i & 31;
      WT1[i] = (k < 7) ? f2bf(We1[k * 256 + n]) : (ushort)0;
    }
  } else {
    if (tid < NCLS) h[tid] = 0;
    __syncthreads();
    for (int i = (b - 289) * 256 + tid; i < P_TOTAL; i += 127 * 256)
      atomicAdd(&h[y[i]], 1);
    __syncthreads();
    if (tid < NCLS) atomicAdd(&counts[tid], h[tid]);
  }
}

// ---------------- fused MLP, 8 waves, N-split /8, feat-in-regs epilogue ----------------
// Layouts (measured m89/m91): A[m=lane&15][k=quad*8+j]; B[n=lane&15][k=quad*8+j];
// C/D: col=lane&15, row=quad*4+reg.
__global__ __launch_bounds__(512, 4) void main_kernel(
    const float* __restrict__ pos, const float* __restrict__ x, const int* __restrict__ y,
    const float* __restrict__ be1, const float* __restrict__ be2,
    const float* __restrict__ b1,  const float* __restrict__ b2,
    const ushort* __restrict__ WT1, const ushort* __restrict__ WT2,
    const ushort* __restrict__ WT3, const ushort* __restrict__ WT4,
    const int* __restrict__ counts, float* __restrict__ gsums,
    float* __restrict__ out) {
  __shared__ ushort actbuf[TP * 264];     // 33792 B: act1 [64][256+8], later act3
  __shared__ ushort chunkbuf[TP * 136];   // 17408 B: A0 [64][40] -> act2 chunks [64][128+8]
  __shared__ float  part[8 * TP];         // 2048 B: per-wave row-norm partials
  __shared__ float  inv_norm[TP];
  __shared__ float  lbl_eff[TP];
  __shared__ int    lbl[TP];

  const int tid  = threadIdx.x;
  const int wave = tid >> 6, lane = tid & 63;
  const int quad = lane >> 4, mrow = lane & 15;
  const long p0 = (long)blockIdx.x * TP;   // 40000 % 64 == 0: block never spans batches
  const int bb = (int)(p0 / NPB);
  const int n0 = (int)(p0 % NPB);
  const f32x4 zero = {0.f, 0.f, 0.f, 0.f};

  // ---- stage A0 = [x(4) | pos(3) | 0...] bf16, stride 40 ----
  for (int i = tid; i < TP * 40; i += 512) {
    int r = i / 40, k = i - r * 40;
    float v = 0.f;
    if (k < 4)      v = x[(bb * 4 + k) * NPB + n0 + r];
    else if (k < 7) v = pos[(p0 + r) * 3 + (k - 4)];
    chunkbuf[r * 40 + k] = f2bf(v);
  }
  if (tid < TP) lbl[tid] = y[p0 + tid];
  __syncthreads();

  // ---- L1: [64x32] @ WT1[256][32]^T -> act1; wave cols wave*32 + nt*16 ----
  {
    f32x4 acc1[4][2];
    #pragma unroll
    for (int mt = 0; mt < 4; mt++) { acc1[mt][0] = zero; acc1[mt][1] = zero; }
    const int kl = quad << 3;
    bf16x8 af[4], bw[2];
    #pragma unroll
    for (int mt = 0; mt < 4; mt++)
      af[mt] = *(const bf16x8*)(chunkbuf + (mt * 16 + mrow) * 40 + kl);
    #pragma unroll
    for (int nt = 0; nt < 2; nt++)
      bw[nt] = *(const bf16x8*)(WT1 + (wave * 32 + nt * 16 + mrow) * 32 + kl);
    #pragma unroll
    for (int nt = 0; nt < 2; nt++)
      #pragma unroll
      for (int mt = 0; mt < 4; mt++)
        acc1[mt][nt] = __builtin_amdgcn_mfma_f32_16x16x32_bf16(af[mt], bw[nt], acc1[mt][nt], 0, 0, 0);
    #pragma unroll
    for (int nt = 0; nt < 2; nt++) {
      int n = wave * 32 + nt * 16 + mrow;
      float bv = be1[n];
      #pragma unroll
      for (int mt = 0; mt < 4; mt++)
        #pragma unroll
        for (int r = 0; r < 4; r++)
          actbuf[(mt * 16 + quad * 4 + r) * 264 + n] = f2bf(fmaxf(acc1[mt][nt][r] + bv, 0.f));
    }
  }
  __syncthreads();

  // ---- fused L2+L3: act2 in 4 chunks of 128 cols; acc3 in regs ----
  f32x4 acc3[4][2];
  #pragma unroll
  for (int mt = 0; mt < 4; mt++) { acc3[mt][0] = zero; acc3[mt][1] = zero; }

  for (int c = 0; c < 4; c++) {
    // L2: wave computes act2 chunk-local cols [wave*16, +16)
    f32x4 acc2[4];
    #pragma unroll
    for (int mt = 0; mt < 4; mt++) acc2[mt] = zero;
    #pragma unroll
    for (int ks = 0; ks < 8; ks++) {
      const int kl = ks * 32 + (quad << 3);
      bf16x8 af[4];
      #pragma unroll
      for (int mt = 0; mt < 4; mt++)
        af[mt] = *(const bf16x8*)(actbuf + (mt * 16 + mrow) * 264 + kl);
      bf16x8 bw = *(const bf16x8*)(WT2 + (long)(c * 128 + wave * 16 + mrow) * 256 + kl);
      #pragma unroll
      for (int mt = 0; mt < 4; mt++)
        acc2[mt] = __builtin_amdgcn_mfma_f32_16x16x32_bf16(af[mt], bw, acc2[mt], 0, 0, 0);
    }
    if (c) __syncthreads();                 // prev chunk's readers done (c=0 covered by act1 barrier)
    {
      int lc = wave * 16 + mrow;            // chunk-local col
      float bv = be2[c * 128 + lc];
      #pragma unroll
      for (int mt = 0; mt < 4; mt++)
        #pragma unroll
        for (int r = 0; r < 4; r++)
          chunkbuf[(mt * 16 + quad * 4 + r) * 136 + lc] = f2bf(fmaxf(acc2[mt][r] + bv, 0.f));
    }
    __syncthreads();
    // L3 accumulate over this chunk's 128 k values; wave cols wave*32 + nt*16
    #pragma unroll
    for (int ks = 0; ks < 4; ks++) {
      const int kl = ks * 32 + (quad << 3);
      bf16x8 af[4], bw[2];
      #pragma unroll
      for (int mt = 0; mt < 4; mt++)
        af[mt] = *(const bf16x8*)(chunkbuf + (mt * 16 + mrow) * 136 + kl);
      #pragma unroll
      for (int nt = 0; nt < 2; nt++)
        bw[nt] = *(const bf16x8*)(WT3 + (long)(wave * 32 + nt * 16 + mrow) * 512 + c * 128 + kl);
      #pragma unroll
      for (int nt = 0; nt < 2; nt++)
        #pragma unroll
        for (int mt = 0; mt < 4; mt++)
          acc3[mt][nt] = __builtin_amdgcn_mfma_f32_16x16x32_bf16(af[mt], bw[nt], acc3[mt][nt], 0, 0, 0);
    }
  }

  // ---- L3 epilogue -> act3 into actbuf (all actbuf/act1 reads pre-date last barrier) ----
  #pragma unroll
  for (int nt = 0; nt < 2; nt++) {
    int n = wave * 32 + nt * 16 + mrow;
    float bv = b1[n];
    #pragma unroll
    for (int mt = 0; mt < 4; mt++)
      #pragma unroll
      for (int r = 0; r < 4; r++)
        actbuf[(mt * 16 + quad * 4 + r) * 264 + n] = f2bf(fmaxf(acc3[mt][nt][r] + bv, 0.f));
  }
  __syncthreads();

  // ---- L4: wave col = wave*16 + mrow; feat stays in registers ----
  f32x4 acc4[4];
  #pragma unroll
  for (int mt = 0; mt < 4; mt++) acc4[mt] = zero;
  #pragma unroll
  for (int ks = 0; ks < 8; ks++) {
    const int kl = ks * 32 + (quad << 3);
    bf16x8 af[4];
    #pragma unroll
    for (int mt = 0; mt < 4; mt++)
      af[mt] = *(const bf16x8*)(actbuf + (mt * 16 + mrow) * 264 + kl);
    bf16x8 bw = *(const bf16x8*)(WT4 + (long)(wave * 16 + mrow) * 256 + kl);
    #pragma unroll
    for (int mt = 0; mt < 4; mt++)
      acc4[mt] = __builtin_amdgcn_mfma_f32_16x16x32_bf16(af[mt], bw, acc4[mt], 0, 0, 0);
  }
  const int col = wave * 16 + mrow;
  float val[4][4];
  {
    float bv = b2[col];
    #pragma unroll
    for (int mt = 0; mt < 4; mt++)
      #pragma unroll
      for (int r = 0; r < 4; r++)
        val[mt][r] = fmaxf(acc4[mt][r] + bv, 0.f);   // bf16 round happens only via MFMA inputs upstream
  }

  // ---- row-norm partials: reduce wave's 16 cols via shfl within quad ----
  #pragma unroll
  for (int mt = 0; mt < 4; mt++)
    #pragma unroll
    for (int r = 0; r < 4; r++) {
      float s = val[mt][r] * val[mt][r];
      s += __shfl_xor(s, 1);  s += __shfl_xor(s, 2);
      s += __shfl_xor(s, 4);  s += __shfl_xor(s, 8);
      if (mrow == 0) part[wave * TP + mt * 16 + quad * 4 + r] = s;
    }
  __syncthreads();
  if (tid < TP) {
    float ss = 0.f;
    #pragma unroll
    for (int w = 0; w < 8; w++) ss += part[w * TP + tid];
    inv_norm[tid] = 1.f / fmaxf(sqrtf(ss), 1e-12f);
    int l = lbl[tid];
    lbl_eff[tid] = (counts[l] >= 256) ? (float)l : -1.f;   // MIN_PTS gate
  }
  __syncthreads();

  // ---- store current_prior from regs + per-class sums ----
  float a[NCLS];
  #pragma unroll
  for (int cc = 0; cc < NCLS; cc++) a[cc] = 0.f;
  #pragma unroll
  for (int mt = 0; mt < 4; mt++)
    #pragma unroll
    for (int r = 0; r < 4; r++) {
      int R = mt * 16 + quad * 4 + r;                  // quad-uniform -> LDS broadcast reads
      float vn = val[mt][r] * inv_norm[R];
      out[(p0 + R) * 129 + col] = vn;                  // 16 lanes/quad -> 64B coalesced
      int cls = lbl[R];
      #pragma unroll
      for (int cc = 0; cc < NCLS; cc++) a[cc] += (cls == cc) ? vn : 0.f;
    }
  if (tid < TP) out[(p0 + tid) * 129 + 128] = lbl_eff[tid];
  #pragma unroll
  for (int cc = 0; cc < NCLS; cc++) {
    a[cc] += __shfl_xor(a[cc], 16);
    a[cc] += __shfl_xor(a[cc], 32);
  }
  if (quad == 0)
    #pragma unroll
    for (int cc = 0; cc < NCLS; cc++) atomicAdd(&gsums[cc * 128 + col], a[cc]);
}

// ---------------- EMA + renorm of prior ----------------
__global__ void finalize_kernel(const float* __restrict__ prior, const int* __restrict__ counts,
                                const float* __restrict__ gsums, float* __restrict__ out) {
  __shared__ float v[NCLS * 128];
  __shared__ float invn[NCLS];
  int tid = threadIdx.x;
  for (int i = tid; i < NCLS * 128; i += 256) {
    int cls = i >> 7;
    int cnt = counts[cls];
    float mean = gsums[i] / fmaxf((float)cnt, 1.f);
    float cur  = (cnt >= 256) ? mean : prior[i];
    v[i] = 0.999f * prior[i] + 0.001f * cur;
  }
  __syncthreads();
  if (tid < NCLS) {
    float s = 0.f;
    for (int c = 0; c < 128; c++) { float t = v[tid * 128 + c]; s += t * t; }
    invn[tid] = 1.f / fmaxf(sqrtf(s), 1e-12f);
  }
  __syncthreads();
  for (int i = tid; i < NCLS * 128; i += 256)
    out[(long)P_TOTAL * 129 + i] = v[i] * invn[i >> 7];
}

extern "C" void kernel_launch(void* const* d_in, const int* in_sizes, int n_in,
                              void* d_out, int out_size, void* d_ws, size_t ws_size,
                              hipStream_t stream) {
  const float* pos   = (const float*)d_in[0];
  const float* x     = (const float*)d_in[1];
  const int*   y     = (const int*)  d_in[2];
  const float* We1   = (const float*)d_in[3];
  const float* be1   = (const float*)d_in[4];
  const float* We2   = (const float*)d_in[5];
  const float* be2   = (const float*)d_in[6];
  const float* W1    = (const float*)d_in[7];
  const float* b1    = (const float*)d_in[8];
  const float* W2    = (const float*)d_in[9];
  const float* b2    = (const float*)d_in[10];
  const float* prior = (const float*)d_in[11];
  float* out = (float*)d_out;

  char* ws = (char*)d_ws;
  int*    counts = (int*)   (ws + 0);        //    64 B
  float*  gsums  = (float*) (ws + 256);      //  6656 B
  ushort* WT1    = (ushort*)(ws + 8192);     // 16384 B  [256][32]
  ushort* WT2    = (ushort*)(ws + 24576);    // 262144 B [512][256]
  ushort* WT3    = (ushort*)(ws + 286720);   // 262144 B [256][512]
  ushort* WT4    = (ushort*)(ws + 548864);   // 65536 B  [128][256]

  hipMemsetAsync(ws, 0, 8192, stream);       // counts + gsums
  prep_all_kernel<<<416, 256, 0, stream>>>(We1, We2, W1, W2, y, WT1, WT2, WT3, WT4, counts);
  main_kernel    <<<P_TOTAL / TP, 512, 0, stream>>>(pos, x, y, be1, be2, b1, b2,
                                                    WT1, WT2, WT3, WT4, counts, gsums, out);
  finalize_kernel<<<1, 256, 0, stream>>>(prior, counts, gsums, out);
}